// Round 4
// baseline (571.609 us; speedup 1.0000x reference)
//
#include <hip/hip_runtime.h>
#include <math.h>

#define T_SEQ 2048
#define C_DIM 2048
#define NH    16
#define NG    4
#define DH    128
#define BATCH 2

typedef unsigned short u16;
typedef __bf16 bf16_t;
typedef bf16_t bf16x8 __attribute__((ext_vector_type(8)));
typedef float  f32x4  __attribute__((ext_vector_type(4)));

static __device__ __forceinline__ u16 f2bf(float f) {
    return __builtin_bit_cast(u16, (__bf16)f);
}

// async global->LDS, 16B per lane. lds must be wave-uniform base; HW adds lane*16.
static __device__ __forceinline__ void gll16(const void* g, void* lds) {
    __builtin_amdgcn_global_load_lds(
        (const __attribute__((address_space(1))) void*)(unsigned long long)(g),
        (__attribute__((address_space(3))) void*)(unsigned int)(unsigned long long)(lds),
        16, 0, 0);
}

// ---------------------------------------------------------------------------
// fp32 -> bf16 cast, 8 elems/thread
// ---------------------------------------------------------------------------
__global__ __launch_bounds__(256)
void cast_f32_bf16(const float* __restrict__ in, u16* __restrict__ out, int n8) {
    int i = blockIdx.x * 256 + threadIdx.x;
    if (i >= n8) return;
    const float4* p = (const float4*)in + (size_t)i * 2;
    float4 a = p[0], b = p[1];
    u16 u[8] = {f2bf(a.x), f2bf(a.y), f2bf(a.z), f2bf(a.w),
                f2bf(b.x), f2bf(b.y), f2bf(b.z), f2bf(b.w)};
    *(uint4*)(out + (size_t)i * 8) = *(const uint4*)u;
}

// ---------------------------------------------------------------------------
// C(fp32, M x N) = A_bf16(M,K) @ B_bf16(N,K)^T (+bias)
// 128x128 tile, BK=32, 4 waves, each wave 64x64 (4x4 MFMA 16x16x32).
// m97 structure: global_load_lds dwordx4 staging, no LDS padding.
// ---------------------------------------------------------------------------
static __device__ __forceinline__ void gemm_body(
        u16* As, u16* Bs,
        const u16* __restrict__ A, const u16* __restrict__ B,
        const float* __restrict__ bias, float* __restrict__ C,
        int N, int K, int m0, int n0) {
    const int t    = threadIdx.x;
    const int lane = t & 63, w = t >> 6;
    const int l15  = lane & 15, quad = lane >> 4;
    const int wr   = w >> 1, wc = w & 1;

    f32x4 acc[4][4];
#pragma unroll
    for (int mt = 0; mt < 4; ++mt)
#pragma unroll
        for (int nt = 0; nt < 4; ++nt) acc[mt][nt] = (f32x4){0.f, 0.f, 0.f, 0.f};

    const int off0 = w*2048 + lane*16;
    const int r0 = off0 >> 6,          c0 = (off0 & 63) >> 1;
    const int r1 = (off0+1024) >> 6,   c1 = ((off0+1024) & 63) >> 1;
    const u16* Ag0 = A + (size_t)(m0 + r0) * K + c0;
    const u16* Ag1 = A + (size_t)(m0 + r1) * K + c1;
    const u16* Bg0 = B + (size_t)(n0 + r0) * K + c0;
    const u16* Bg1 = B + (size_t)(n0 + r1) * K + c1;
    char* AsB = (char*)As; char* BsB = (char*)Bs;
    const int ldsOff0 = w*2048, ldsOff1 = w*2048 + 1024;

    for (int k0 = 0; k0 < K; k0 += 32) {
        gll16(Ag0 + k0, AsB + ldsOff0);
        gll16(Ag1 + k0, AsB + ldsOff1);
        gll16(Bg0 + k0, BsB + ldsOff0);
        gll16(Bg1 + k0, BsB + ldsOff1);
        __syncthreads();
        bf16x8 af[4], bf[4];
#pragma unroll
        for (int mt = 0; mt < 4; ++mt)
            af[mt] = __builtin_bit_cast(bf16x8,
                *(const uint4*)&As[(wr*64 + mt*16 + l15)*32 + quad*8]);
#pragma unroll
        for (int nt = 0; nt < 4; ++nt)
            bf[nt] = __builtin_bit_cast(bf16x8,
                *(const uint4*)&Bs[(wc*64 + nt*16 + l15)*32 + quad*8]);
#pragma unroll
        for (int mt = 0; mt < 4; ++mt)
#pragma unroll
            for (int nt = 0; nt < 4; ++nt)
                acc[mt][nt] = __builtin_amdgcn_mfma_f32_16x16x32_bf16(
                                  af[mt], bf[nt], acc[mt][nt], 0, 0, 0);
        __syncthreads();
    }

#pragma unroll
    for (int mt = 0; mt < 4; ++mt)
#pragma unroll
        for (int nt = 0; nt < 4; ++nt) {
            const int col = n0 + wc*64 + nt*16 + l15;
            const float bv = bias ? bias[col] : 0.f;
#pragma unroll
            for (int r = 0; r < 4; ++r) {
                const int row = m0 + wr*64 + mt*16 + quad*4 + r;
                C[(size_t)row * N + col] = acc[mt][nt][r] + bv;
            }
        }
}

__global__ __launch_bounds__(256)
void gemm_nt_bf16(const u16* __restrict__ A, const u16* __restrict__ B,
                  const float* __restrict__ bias, float* __restrict__ C,
                  int N, int K) {
    __shared__ __align__(16) u16 As[128*32];
    __shared__ __align__(16) u16 Bs[128*32];
    gemm_body(As, Bs, A, B, bias, C, N, K, blockIdx.y*128, blockIdx.x*128);
}

__global__ __launch_bounds__(256)
void gemm_nt_bf16_kv(const u16* __restrict__ A,
                     const u16* __restrict__ Bk, const u16* __restrict__ Bv,
                     float* __restrict__ Ck, float* __restrict__ Cv,
                     int N, int K) {
    __shared__ __align__(16) u16 As[128*32];
    __shared__ __align__(16) u16 Bs[128*32];
    const u16* B = blockIdx.z ? Bv : Bk;
    float*     C = blockIdx.z ? Cv : Ck;
    gemm_body(As, Bs, A, B, nullptr, C, N, K, blockIdx.y*128, blockIdx.x*128);
}

// ---------------------------------------------------------------------------
// RMSNorm + RoPE, fp32 in -> bf16 out (pre-scaled by `scale`).
// ---------------------------------------------------------------------------
__global__ __launch_bounds__(256)
void rmsnorm_rope_cast(const float* __restrict__ in, const float* __restrict__ w,
                       u16* __restrict__ out, int nheads, float scale) {
    const int row  = blockIdx.x * 4 + (threadIdx.x >> 6);
    const int lane = threadIdx.x & 63;
    const float* p = in + (size_t)row * 128;
    float x1 = p[lane], x2 = p[lane + 64];
    float ss = x1*x1 + x2*x2;
#pragma unroll
    for (int off = 32; off >= 1; off >>= 1) ss += __shfl_xor(ss, off, 64);
    float inv = 1.0f / (sqrtf(ss * (1.0f/128.0f)) + 1e-6f);
    float x1n = w[lane]      * x1 * inv;
    float x2n = w[lane + 64] * x2 * inv;
    int tpos = (row / nheads) & (T_SEQ - 1);
    float invfreq = powf(10000.0f, -(float)lane / 64.0f);
    float s, c;
    sincosf((float)tpos * invfreq, &s, &c);
    out[(size_t)row*128 + lane]      = f2bf((x1n * c + x2n * s) * scale);
    out[(size_t)row*128 + lane + 64] = f2bf((x2n * c - x1n * s) * scale);
}

// ---------------------------------------------------------------------------
// V cast fp32->bf16 + transpose: v (B,T,G,D) -> vt (B,G,D,T).
// ---------------------------------------------------------------------------
__global__ __launch_bounds__(256)
void v_cast_transpose(const float* __restrict__ v, u16* __restrict__ vt) {
    __shared__ u16 Lt[128 * 66];
    const int t  = threadIdx.x;
    const int t0 = blockIdx.x * 64;
    const int bg = blockIdx.y;
    const int b  = bg / NG, g = bg % NG;
#pragma unroll
    for (int rep = 0; rep < 8; ++rep) {
        int idx = rep * 256 + t;
        int i   = idx >> 5;
        int c   = idx & 31;
        float4 f = *(const float4*)(v + ((size_t)(b*T_SEQ + t0 + i)*NG + g)*DH + c*4);
        Lt[(c*4+0)*66 + i] = f2bf(f.x);
        Lt[(c*4+1)*66 + i] = f2bf(f.y);
        Lt[(c*4+2)*66 + i] = f2bf(f.z);
        Lt[(c*4+3)*66 + i] = f2bf(f.w);
    }
    __syncthreads();
#pragma unroll
    for (int rep = 0; rep < 4; ++rep) {
        int idx = rep * 256 + t;
        int d = idx >> 3, c = idx & 7;
        const u16* src = &Lt[d*66 + c*8];
        uint4 val;
        val.x = *(const unsigned int*)(src + 0);
        val.y = *(const unsigned int*)(src + 2);
        val.z = *(const unsigned int*)(src + 4);
        val.w = *(const unsigned int*)(src + 6);
        *(uint4*)(vt + ((size_t)(bg*DH + d))*T_SEQ + t0 + c*8) = val;
    }
}

// ---------------------------------------------------------------------------
// MFMA flash attention v2 (bf16 in, fp32 accum, bf16 y out).
// FIXED softmax shift: soft-cap bounds scores to (-50,50), so p = exp(sc)
// needs no running max, no rescale, no per-iteration reductions.
// p = exp2(C2 - C3 / (exp2(s*C1) + 1)); row-sum reduced once at the end.
// blockIdx.x reversed so heavy (long-K) blocks dispatch first.
// ---------------------------------------------------------------------------
#define KPAD 136
#define VPAD 72
#define PPAD 72

__global__ __launch_bounds__(256)
void flash_attn_mfma(const u16* __restrict__ qh, const u16* __restrict__ kh,
                     const u16* __restrict__ vt, u16* __restrict__ y) {
    __shared__ __align__(16) u16 Ks [64  * KPAD];
    __shared__ __align__(16) u16 Vts[128 * VPAD];
    __shared__ __align__(16) u16 Ps [64  * PPAD];

    const int t    = threadIdx.x;
    const int lane = t & 63, w = t >> 6;
    const int l15  = lane & 15, quad = lane >> 4;
    const int q0   = (gridDim.x - 1 - blockIdx.x) * 64;   // long blocks first
    const int bh   = blockIdx.y;
    const int b    = bh / NH, h = bh % NH;
    const int g    = h / (NH / NG);

    const float C1 = 0.057707801635558536f;   // 0.04 * log2(e)
    const float C2 = 72.13475204444817f;      // 50 * log2(e)
    const float C3 = 144.26950408889634f;     // 100 * log2(e)

    bf16x8 aq[4];
    const u16* qp = qh + ((size_t)(b*T_SEQ + q0 + w*16 + l15) * NH + h) * DH;
#pragma unroll
    for (int kc = 0; kc < 4; ++kc)
        aq[kc] = __builtin_bit_cast(bf16x8, *(const uint4*)(qp + kc*32 + quad*8));

    f32x4 accO[8];
#pragma unroll
    for (int nd = 0; nd < 8; ++nd) accO[nd] = (f32x4){0.f, 0.f, 0.f, 0.f};
    float ls[4] = {0.f, 0.f, 0.f, 0.f};      // per-lane partial row sums

    const int ktiles = q0 / 64 + 1;
    for (int kt = 0; kt < ktiles; ++kt) {
        const int k0 = kt * 64;
#pragma unroll
        for (int rep = 0; rep < 4; ++rep) {
            int idx = rep * 256 + t;
            int r = idx >> 4, c = idx & 15;
            *(uint4*)&Ks[r*KPAD + c*8] =
                *(const uint4*)(kh + ((size_t)(b*T_SEQ + k0 + r)*NG + g)*DH + c*8);
        }
        const u16* vbase = vt + ((size_t)(b*NG + g)*DH)*T_SEQ + k0;
#pragma unroll
        for (int rep = 0; rep < 4; ++rep) {
            int idx = rep * 256 + t;
            int d = idx >> 3, c = idx & 7;
            *(uint4*)&Vts[d*VPAD + c*8] =
                *(const uint4*)(vbase + (size_t)d*T_SEQ + c*8);
        }
        __syncthreads();

        // --- S = Q K^T (16x64 per wave) ---
        f32x4 accS[4];
#pragma unroll
        for (int nt = 0; nt < 4; ++nt) accS[nt] = (f32x4){0.f, 0.f, 0.f, 0.f};
#pragma unroll
        for (int nt = 0; nt < 4; ++nt)
#pragma unroll
            for (int kc = 0; kc < 4; ++kc) {
                bf16x8 bk = __builtin_bit_cast(bf16x8,
                    *(const uint4*)&Ks[(nt*16 + l15)*KPAD + kc*32 + quad*8]);
                accS[nt] = __builtin_amdgcn_mfma_f32_16x16x32_bf16(aq[kc], bk, accS[nt], 0, 0, 0);
            }

        // --- soft-cap + causal + exp (fixed shift), accumulate row sums ---
#pragma unroll
        for (int nt = 0; nt < 4; ++nt) {
            const int colg = k0 + nt*16 + l15;
#pragma unroll
            for (int r = 0; r < 4; ++r) {
                const int rowg = q0 + w*16 + quad*4 + r;
                float s  = accS[nt][r];
                float t1 = __builtin_amdgcn_exp2f(s * C1);
                float p  = __builtin_amdgcn_exp2f(
                               fmaf(-C3, __builtin_amdgcn_rcpf(t1 + 1.f), C2));
                p = (colg > rowg) ? 0.f : p;
                ls[r] += p;
                Ps[(w*16 + quad*4 + r)*PPAD + nt*16 + l15] = f2bf(p);
            }
        }

        bf16x8 ap[2];
#pragma unroll
        for (int kc = 0; kc < 2; ++kc)
            ap[kc] = __builtin_bit_cast(bf16x8,
                *(const uint4*)&Ps[(w*16 + l15)*PPAD + kc*32 + quad*8]);

#pragma unroll
        for (int nd = 0; nd < 8; ++nd)
#pragma unroll
            for (int kc = 0; kc < 2; ++kc) {
                bf16x8 bv = __builtin_bit_cast(bf16x8,
                    *(const uint4*)&Vts[(nd*16 + l15)*VPAD + kc*32 + quad*8]);
                accO[nd] = __builtin_amdgcn_mfma_f32_16x16x32_bf16(ap[kc], bv, accO[nd], 0, 0, 0);
            }
        __syncthreads();
    }

    // --- one final row-sum reduction across the 16 l15 lanes ---
#pragma unroll
    for (int r = 0; r < 4; ++r) {
        float v = ls[r];
        v += __shfl_xor(v, 1, 64);
        v += __shfl_xor(v, 2, 64);
        v += __shfl_xor(v, 4, 64);
        v += __shfl_xor(v, 8, 64);
        ls[r] = v;
    }

#pragma unroll
    for (int r = 0; r < 4; ++r) {
        float invl = 1.f / ls[r];
        u16* yp = y + (size_t)(b*T_SEQ + q0 + w*16 + quad*4 + r) * C_DIM + h*DH;
#pragma unroll
        for (int nd = 0; nd < 8; ++nd)
            yp[nd*16 + l15] = f2bf(accO[nd][r] * invl);
    }
}

// ---------------------------------------------------------------------------
extern "C" void kernel_launch(void* const* d_in, const int* in_sizes, int n_in,
                              void* d_out, int out_size, void* d_ws, size_t ws_size,
                              hipStream_t stream) {
    const float* x  = (const float*)d_in[0];
    const float* Wq = (const float*)d_in[1];
    const float* Wk = (const float*)d_in[2];
    const float* Wv = (const float*)d_in[3];
    const float* Wo = (const float*)d_in[4];
    const float* bo = (const float*)d_in[5];
    const float* qw = (const float*)d_in[6];
    const float* kw = (const float*)d_in[7];
    float* out = (float*)d_out;

    const size_t qE = (size_t)BATCH * T_SEQ * NH * DH;   // 8,388,608
    const size_t kE = (size_t)BATCH * T_SEQ * NG * DH;   // 2,097,152
    const size_t wqE = (size_t)C_DIM * C_DIM;            // 4,194,304
    const size_t wkE = (size_t)(NG*DH) * C_DIM;          // 1,048,576

    float* qf  = (float*)d_ws;          // qE floats
    float* kf  = qf + qE;               // kE floats
    float* vf  = kf + kE;               // kE floats
    u16*   qh  = (u16*)(vf + kE);       // qE
    u16*   khb = qh + qE;               // kE
    u16*   vtb = khb + kE;              // kE
    u16*   xh  = vtb + kE;              // qE
    u16*   wqh = xh + qE;               // wqE
    u16*   wkh = wqh + wqE;             // wkE
    u16*   wvh = wkh + wkE;             // wkE
    u16*   woh = (u16*)kf;              // wqE (reuses kf: dead after rmsnorm_k)
    u16*   yh  = (u16*)qf;              // qE  (reuses qf: dead after rmsnorm_q)

    const int M = BATCH * T_SEQ;   // 4096
    dim3 blk(256);

    cast_f32_bf16<<<dim3(qE/8/256),  blk, 0, stream>>>(x,  xh,  qE/8);
    cast_f32_bf16<<<dim3(wqE/8/256), blk, 0, stream>>>(Wq, wqh, wqE/8);
    cast_f32_bf16<<<dim3(wkE/8/256), blk, 0, stream>>>(Wk, wkh, wkE/8);
    cast_f32_bf16<<<dim3(wkE/8/256), blk, 0, stream>>>(Wv, wvh, wkE/8);

    gemm_nt_bf16<<<dim3(C_DIM/128, M/128), blk, 0, stream>>>(xh, wqh, nullptr, qf, C_DIM, C_DIM);
    gemm_nt_bf16_kv<<<dim3((NG*DH)/128, M/128, 2), blk, 0, stream>>>(xh, wkh, wvh, kf, vf, NG*DH, C_DIM);

    rmsnorm_rope_cast<<<dim3(M * NH / 4), blk, 0, stream>>>(qf, qw, qh, NH, 0.08838834764831845f);
    rmsnorm_rope_cast<<<dim3(M * NG / 4), blk, 0, stream>>>(kf, kw, khb, NG, 1.0f);
    v_cast_transpose<<<dim3(T_SEQ/64, BATCH*NG), blk, 0, stream>>>(vf, vtb);

    cast_f32_bf16<<<dim3(wqE/8/256), blk, 0, stream>>>(Wo, woh, wqE/8);

    flash_attn_mfma<<<dim3(T_SEQ/64, BATCH*NH), blk, 0, stream>>>(qh, khb, vtb, yh);

    gemm_nt_bf16<<<dim3(C_DIM/128, M/128), blk, 0, stream>>>(yh, woh, bo, out, C_DIM, C_DIM);
}

// Round 5
// 443.690 us; speedup vs baseline: 1.2883x; 1.2883x over previous
//
#include <hip/hip_runtime.h>
#include <math.h>

#define T_SEQ 2048
#define C_DIM 2048
#define NH    16
#define NG    4
#define DH    128
#define BATCH 2

typedef unsigned short u16;
typedef __bf16 bf16_t;
typedef bf16_t bf16x8 __attribute__((ext_vector_type(8)));
typedef float  f32x4  __attribute__((ext_vector_type(4)));

static __device__ __forceinline__ u16 f2bf(float f) {
    return __builtin_bit_cast(u16, (__bf16)f);
}

// async global->LDS, 16B per lane. lds must be wave-uniform base; HW adds lane*16.
static __device__ __forceinline__ void gll16(const void* g, void* lds) {
    __builtin_amdgcn_global_load_lds(
        (const __attribute__((address_space(1))) void*)(unsigned long long)(g),
        (__attribute__((address_space(3))) void*)(unsigned int)(unsigned long long)(lds),
        16, 0, 0);
}

// ---------------------------------------------------------------------------
// fp32 -> bf16 cast, 8 elems/thread
// ---------------------------------------------------------------------------
__global__ __launch_bounds__(256)
void cast_f32_bf16(const float* __restrict__ in, u16* __restrict__ out, int n8) {
    int i = blockIdx.x * 256 + threadIdx.x;
    if (i >= n8) return;
    const float4* p = (const float4*)in + (size_t)i * 2;
    float4 a = p[0], b = p[1];
    u16 u[8] = {f2bf(a.x), f2bf(a.y), f2bf(a.z), f2bf(a.w),
                f2bf(b.x), f2bf(b.y), f2bf(b.z), f2bf(b.w)};
    *(uint4*)(out + (size_t)i * 8) = *(const uint4*)u;
}

// ---------------------------------------------------------------------------
// C(fp32, M x N) = A_bf16(M,K) @ B_bf16(N,K)^T (+bias)
// 128x128 tile, BK=32, 4 waves, each wave 64x64 (4x4 MFMA 16x16x32).
// ---------------------------------------------------------------------------
static __device__ __forceinline__ void gemm_body(
        u16* As, u16* Bs,
        const u16* __restrict__ A, const u16* __restrict__ B,
        const float* __restrict__ bias, float* __restrict__ C,
        int N, int K, int m0, int n0) {
    const int t    = threadIdx.x;
    const int lane = t & 63, w = t >> 6;
    const int l15  = lane & 15, quad = lane >> 4;
    const int wr   = w >> 1, wc = w & 1;

    f32x4 acc[4][4];
#pragma unroll
    for (int mt = 0; mt < 4; ++mt)
#pragma unroll
        for (int nt = 0; nt < 4; ++nt) acc[mt][nt] = (f32x4){0.f, 0.f, 0.f, 0.f};

    const int off0 = w*2048 + lane*16;
    const int r0 = off0 >> 6,          c0 = (off0 & 63) >> 1;
    const int r1 = (off0+1024) >> 6,   c1 = ((off0+1024) & 63) >> 1;
    const u16* Ag0 = A + (size_t)(m0 + r0) * K + c0;
    const u16* Ag1 = A + (size_t)(m0 + r1) * K + c1;
    const u16* Bg0 = B + (size_t)(n0 + r0) * K + c0;
    const u16* Bg1 = B + (size_t)(n0 + r1) * K + c1;
    char* AsB = (char*)As; char* BsB = (char*)Bs;
    const int ldsOff0 = w*2048, ldsOff1 = w*2048 + 1024;

    for (int k0 = 0; k0 < K; k0 += 32) {
        gll16(Ag0 + k0, AsB + ldsOff0);
        gll16(Ag1 + k0, AsB + ldsOff1);
        gll16(Bg0 + k0, BsB + ldsOff0);
        gll16(Bg1 + k0, BsB + ldsOff1);
        __syncthreads();
        bf16x8 af[4], bf[4];
#pragma unroll
        for (int mt = 0; mt < 4; ++mt)
            af[mt] = __builtin_bit_cast(bf16x8,
                *(const uint4*)&As[(wr*64 + mt*16 + l15)*32 + quad*8]);
#pragma unroll
        for (int nt = 0; nt < 4; ++nt)
            bf[nt] = __builtin_bit_cast(bf16x8,
                *(const uint4*)&Bs[(wc*64 + nt*16 + l15)*32 + quad*8]);
#pragma unroll
        for (int mt = 0; mt < 4; ++mt)
#pragma unroll
            for (int nt = 0; nt < 4; ++nt)
                acc[mt][nt] = __builtin_amdgcn_mfma_f32_16x16x32_bf16(
                                  af[mt], bf[nt], acc[mt][nt], 0, 0, 0);
        __syncthreads();
    }

#pragma unroll
    for (int mt = 0; mt < 4; ++mt)
#pragma unroll
        for (int nt = 0; nt < 4; ++nt) {
            const int col = n0 + wc*64 + nt*16 + l15;
            const float bv = bias ? bias[col] : 0.f;
#pragma unroll
            for (int r = 0; r < 4; ++r) {
                const int row = m0 + wr*64 + mt*16 + quad*4 + r;
                C[(size_t)row * N + col] = acc[mt][nt][r] + bv;
            }
        }
}

__global__ __launch_bounds__(256)
void gemm_nt_bf16(const u16* __restrict__ A, const u16* __restrict__ B,
                  const float* __restrict__ bias, float* __restrict__ C,
                  int N, int K) {
    __shared__ __align__(16) u16 As[128*32];
    __shared__ __align__(16) u16 Bs[128*32];
    gemm_body(As, Bs, A, B, bias, C, N, K, blockIdx.y*128, blockIdx.x*128);
}

__global__ __launch_bounds__(256)
void gemm_nt_bf16_kv(const u16* __restrict__ A,
                     const u16* __restrict__ Bk, const u16* __restrict__ Bv,
                     float* __restrict__ Ck, float* __restrict__ Cv,
                     int N, int K) {
    __shared__ __align__(16) u16 As[128*32];
    __shared__ __align__(16) u16 Bs[128*32];
    const u16* B = blockIdx.z ? Bv : Bk;
    float*     C = blockIdx.z ? Cv : Ck;
    gemm_body(As, Bs, A, B, nullptr, C, N, K, blockIdx.y*128, blockIdx.x*128);
}

// ---------------------------------------------------------------------------
// RMSNorm + RoPE, fp32 in -> bf16 out (pre-scaled by `scale`).
// ---------------------------------------------------------------------------
__global__ __launch_bounds__(256)
void rmsnorm_rope_cast(const float* __restrict__ in, const float* __restrict__ w,
                       u16* __restrict__ out, int nheads, float scale) {
    const int row  = blockIdx.x * 4 + (threadIdx.x >> 6);
    const int lane = threadIdx.x & 63;
    const float* p = in + (size_t)row * 128;
    float x1 = p[lane], x2 = p[lane + 64];
    float ss = x1*x1 + x2*x2;
#pragma unroll
    for (int off = 32; off >= 1; off >>= 1) ss += __shfl_xor(ss, off, 64);
    float inv = 1.0f / (sqrtf(ss * (1.0f/128.0f)) + 1e-6f);
    float x1n = w[lane]      * x1 * inv;
    float x2n = w[lane + 64] * x2 * inv;
    int tpos = (row / nheads) & (T_SEQ - 1);
    float invfreq = powf(10000.0f, -(float)lane / 64.0f);
    float s, c;
    sincosf((float)tpos * invfreq, &s, &c);
    out[(size_t)row*128 + lane]      = f2bf((x1n * c + x2n * s) * scale);
    out[(size_t)row*128 + lane + 64] = f2bf((x2n * c - x1n * s) * scale);
}

// ---------------------------------------------------------------------------
// V cast fp32->bf16 + transpose: v (B,T,G,D) -> vt (B,G,D,T).
// ---------------------------------------------------------------------------
__global__ __launch_bounds__(256)
void v_cast_transpose(const float* __restrict__ v, u16* __restrict__ vt) {
    __shared__ u16 Lt[128 * 66];
    const int t  = threadIdx.x;
    const int t0 = blockIdx.x * 64;
    const int bg = blockIdx.y;
    const int b  = bg / NG, g = bg % NG;
#pragma unroll
    for (int rep = 0; rep < 8; ++rep) {
        int idx = rep * 256 + t;
        int i   = idx >> 5;
        int c   = idx & 31;
        float4 f = *(const float4*)(v + ((size_t)(b*T_SEQ + t0 + i)*NG + g)*DH + c*4);
        Lt[(c*4+0)*66 + i] = f2bf(f.x);
        Lt[(c*4+1)*66 + i] = f2bf(f.y);
        Lt[(c*4+2)*66 + i] = f2bf(f.z);
        Lt[(c*4+3)*66 + i] = f2bf(f.w);
    }
    __syncthreads();
#pragma unroll
    for (int rep = 0; rep < 4; ++rep) {
        int idx = rep * 256 + t;
        int d = idx >> 3, c = idx & 7;
        const u16* src = &Lt[d*66 + c*8];
        uint4 val;
        val.x = *(const unsigned int*)(src + 0);
        val.y = *(const unsigned int*)(src + 2);
        val.z = *(const unsigned int*)(src + 4);
        val.w = *(const unsigned int*)(src + 6);
        *(uint4*)(vt + ((size_t)(bg*DH + d))*T_SEQ + t0 + c*8) = val;
    }
}

// ---------------------------------------------------------------------------
// MFMA flash attention v3: GQA-shared K/V staging.
// Block = 512 thr = 8 waves = 4 heads (one group) x 32 queries.
// Wave w: head g*4 + (w&3), q-rows q0 + (w>>2)*16 .. +15.
// One 64-key K/V staging feeds all 8 waves (4x arithmetic intensity vs v2).
// Soft-cap via odd poly tanh (|s| <= 11.4 by Cauchy-Schwarz after RMSNorm).
// LDS 54272 B -> 3 blocks/CU.
// ---------------------------------------------------------------------------
#define KPAD 136
#define VPAD 72
#define PPAD 72

__global__ __launch_bounds__(512)
void flash_attn_mfma(const u16* __restrict__ qh, const u16* __restrict__ kh,
                     const u16* __restrict__ vt, u16* __restrict__ y) {
    __shared__ __align__(16) u16 Ks [64  * KPAD];   // 64 keys x 128 d
    __shared__ __align__(16) u16 Vts[128 * VPAD];   // 128 d  x 64 keys
    __shared__ __align__(16) u16 Ps [128 * PPAD];   // 8 waves x 16 rows x 64 keys

    const int t    = threadIdx.x;
    const int lane = t & 63, w = t >> 6;            // w = 0..7
    const int l15  = lane & 15, quad = lane >> 4;
    const int q0   = (int)(gridDim.x - 1 - blockIdx.x) * 32;  // heavy first
    const int bg   = blockIdx.y;
    const int b    = bg / NG, g = bg % NG;
    const int h    = g * (NH / NG) + (w & 3);
    const int qrow0 = q0 + (w >> 2) * 16;

    const float L2E = 1.4426950408889634f;

    bf16x8 aq[4];
    const u16* qp = qh + ((size_t)(b*T_SEQ + qrow0 + l15) * NH + h) * DH;
#pragma unroll
    for (int kc = 0; kc < 4; ++kc)
        aq[kc] = __builtin_bit_cast(bf16x8, *(const uint4*)(qp + kc*32 + quad*8));

    f32x4 accO[8];
#pragma unroll
    for (int nd = 0; nd < 8; ++nd) accO[nd] = (f32x4){0.f, 0.f, 0.f, 0.f};
    float ls[4] = {0.f, 0.f, 0.f, 0.f};

    const int ktiles = q0 / 64 + 1;
    for (int kt = 0; kt < ktiles; ++kt) {
        const int k0 = kt * 64;
        // --- stage K: 64 rows x 16 chunks(16B), 1024 items / 512 thr ---
#pragma unroll
        for (int rep = 0; rep < 2; ++rep) {
            int idx = rep * 512 + t;
            int r = idx >> 4, c = idx & 15;
            *(uint4*)&Ks[r*KPAD + c*8] =
                *(const uint4*)(kh + ((size_t)(b*T_SEQ + k0 + r)*NG + g)*DH + c*8);
        }
        // --- stage V^T: 128 d-rows x 8 chunks(16B) ---
        const u16* vbase = vt + ((size_t)(b*NG + g)*DH)*T_SEQ + k0;
#pragma unroll
        for (int rep = 0; rep < 2; ++rep) {
            int idx = rep * 512 + t;
            int d = idx >> 3, c = idx & 7;
            *(uint4*)&Vts[d*VPAD + c*8] =
                *(const uint4*)(vbase + (size_t)d*T_SEQ + c*8);
        }
        __syncthreads();

        // --- S = Q K^T (16x64 per wave) ---
        f32x4 accS[4];
#pragma unroll
        for (int nt = 0; nt < 4; ++nt) accS[nt] = (f32x4){0.f, 0.f, 0.f, 0.f};
#pragma unroll
        for (int nt = 0; nt < 4; ++nt)
#pragma unroll
            for (int kc = 0; kc < 4; ++kc) {
                bf16x8 bk = __builtin_bit_cast(bf16x8,
                    *(const uint4*)&Ks[(nt*16 + l15)*KPAD + kc*32 + quad*8]);
                accS[nt] = __builtin_amdgcn_mfma_f32_16x16x32_bf16(aq[kc], bk, accS[nt], 0, 0, 0);
            }

        // --- soft-cap (poly tanh) + causal + exp2, accumulate row sums ---
#pragma unroll
        for (int nt = 0; nt < 4; ++nt) {
            const int colg = k0 + nt*16 + l15;
#pragma unroll
            for (int r = 0; r < 4; ++r) {
                const int rowg = qrow0 + quad*4 + r;
                float s = accS[nt][r];
                float z = s * 0.02f;          // s/50
                float u = z * z;              // <= 0.052
                // tanh(z)/z = 1 - u/3 + 2u^2/15 - 17u^3/315  (err < 1e-7)
                float poly = fmaf(u, fmaf(u, fmaf(u, -0.05396825396825397f,
                                       0.13333333333333333f),
                                      -0.3333333333333333f), 1.0f);
                float p = __builtin_amdgcn_exp2f(s * poly * L2E);
                p = (colg > rowg) ? 0.f : p;
                ls[r] += p;
                Ps[(w*16 + quad*4 + r)*PPAD + nt*16 + l15] = f2bf(p);
            }
        }

        bf16x8 ap[2];
#pragma unroll
        for (int kc = 0; kc < 2; ++kc)
            ap[kc] = __builtin_bit_cast(bf16x8,
                *(const uint4*)&Ps[(w*16 + l15)*PPAD + kc*32 + quad*8]);

#pragma unroll
        for (int nd = 0; nd < 8; ++nd)
#pragma unroll
            for (int kc = 0; kc < 2; ++kc) {
                bf16x8 bv = __builtin_bit_cast(bf16x8,
                    *(const uint4*)&Vts[(nd*16 + l15)*VPAD + kc*32 + quad*8]);
                accO[nd] = __builtin_amdgcn_mfma_f32_16x16x32_bf16(ap[kc], bv, accO[nd], 0, 0, 0);
            }
        __syncthreads();
    }

    // --- final row-sum reduction across the 16 l15 lanes ---
#pragma unroll
    for (int r = 0; r < 4; ++r) {
        float v = ls[r];
        v += __shfl_xor(v, 1, 64);
        v += __shfl_xor(v, 2, 64);
        v += __shfl_xor(v, 4, 64);
        v += __shfl_xor(v, 8, 64);
        ls[r] = v;
    }

#pragma unroll
    for (int r = 0; r < 4; ++r) {
        float invl = 1.f / ls[r];
        u16* yp = y + (size_t)(b*T_SEQ + qrow0 + quad*4 + r) * C_DIM + h*DH;
#pragma unroll
        for (int nd = 0; nd < 8; ++nd)
            yp[nd*16 + l15] = f2bf(accO[nd][r] * invl);
    }
}

// ---------------------------------------------------------------------------
extern "C" void kernel_launch(void* const* d_in, const int* in_sizes, int n_in,
                              void* d_out, int out_size, void* d_ws, size_t ws_size,
                              hipStream_t stream) {
    const float* x  = (const float*)d_in[0];
    const float* Wq = (const float*)d_in[1];
    const float* Wk = (const float*)d_in[2];
    const float* Wv = (const float*)d_in[3];
    const float* Wo = (const float*)d_in[4];
    const float* bo = (const float*)d_in[5];
    const float* qw = (const float*)d_in[6];
    const float* kw = (const float*)d_in[7];
    float* out = (float*)d_out;

    const size_t qE = (size_t)BATCH * T_SEQ * NH * DH;   // 8,388,608
    const size_t kE = (size_t)BATCH * T_SEQ * NG * DH;   // 2,097,152
    const size_t wqE = (size_t)C_DIM * C_DIM;            // 4,194,304
    const size_t wkE = (size_t)(NG*DH) * C_DIM;          // 1,048,576

    float* qf  = (float*)d_ws;          // qE floats
    float* kf  = qf + qE;               // kE floats
    float* vf  = kf + kE;               // kE floats
    u16*   qh  = (u16*)(vf + kE);       // qE
    u16*   khb = qh + qE;               // kE
    u16*   vtb = khb + kE;              // kE
    u16*   xh  = vtb + kE;              // qE
    u16*   wqh = xh + qE;               // wqE
    u16*   wkh = wqh + wqE;             // wkE
    u16*   wvh = wkh + wkE;             // wkE
    u16*   woh = (u16*)kf;              // wqE (reuses kf: dead after rmsnorm_k)
    u16*   yh  = (u16*)qf;              // qE  (reuses qf: dead after rmsnorm_q)

    const int M = BATCH * T_SEQ;   // 4096
    dim3 blk(256);

    cast_f32_bf16<<<dim3(qE/8/256),  blk, 0, stream>>>(x,  xh,  qE/8);
    cast_f32_bf16<<<dim3(wqE/8/256), blk, 0, stream>>>(Wq, wqh, wqE/8);
    cast_f32_bf16<<<dim3(wkE/8/256), blk, 0, stream>>>(Wk, wkh, wkE/8);
    cast_f32_bf16<<<dim3(wkE/8/256), blk, 0, stream>>>(Wv, wvh, wkE/8);

    gemm_nt_bf16<<<dim3(C_DIM/128, M/128), blk, 0, stream>>>(xh, wqh, nullptr, qf, C_DIM, C_DIM);
    gemm_nt_bf16_kv<<<dim3((NG*DH)/128, M/128, 2), blk, 0, stream>>>(xh, wkh, wvh, kf, vf, NG*DH, C_DIM);

    rmsnorm_rope_cast<<<dim3(M * NH / 4), blk, 0, stream>>>(qf, qw, qh, NH, 0.08838834764831845f);
    rmsnorm_rope_cast<<<dim3(M * NG / 4), blk, 0, stream>>>(kf, kw, khb, NG, 1.0f);
    v_cast_transpose<<<dim3(T_SEQ/64, BATCH*NG), blk, 0, stream>>>(vf, vtb);

    cast_f32_bf16<<<dim3(wqE/8/256), blk, 0, stream>>>(Wo, woh, wqE/8);

    flash_attn_mfma<<<dim3(T_SEQ/32, BATCH*NG), dim3(512), 0, stream>>>(qh, khb, vtb, yh);

    gemm_nt_bf16<<<dim3(C_DIM/128, M/128), blk, 0, stream>>>(yh, woh, bo, out, C_DIM, C_DIM);
}

// Round 6
// 430.900 us; speedup vs baseline: 1.3265x; 1.0297x over previous
//
#include <hip/hip_runtime.h>
#include <math.h>

#define T_SEQ 2048
#define C_DIM 2048
#define NH    16
#define NG    4
#define DH    128
#define BATCH 2

typedef unsigned short u16;
typedef __bf16 bf16_t;
typedef bf16_t bf16x8 __attribute__((ext_vector_type(8)));
typedef float  f32x4  __attribute__((ext_vector_type(4)));

static __device__ __forceinline__ u16 f2bf(float f) {
    return __builtin_bit_cast(u16, (__bf16)f);
}

// async global->LDS, 16B per lane. lds must be wave-uniform base; HW adds lane*16.
static __device__ __forceinline__ void gll16(const void* g, void* lds) {
    __builtin_amdgcn_global_load_lds(
        (const __attribute__((address_space(1))) void*)(unsigned long long)(g),
        (__attribute__((address_space(3))) void*)(unsigned int)(unsigned long long)(lds),
        16, 0, 0);
}

// ---------------------------------------------------------------------------
// fp32 -> bf16 cast, 8 elems/thread
// ---------------------------------------------------------------------------
__global__ __launch_bounds__(256)
void cast_f32_bf16(const float* __restrict__ in, u16* __restrict__ out, int n8) {
    int i = blockIdx.x * 256 + threadIdx.x;
    if (i >= n8) return;
    const float4* p = (const float4*)in + (size_t)i * 2;
    float4 a = p[0], b = p[1];
    u16 u[8] = {f2bf(a.x), f2bf(a.y), f2bf(a.z), f2bf(a.w),
                f2bf(b.x), f2bf(b.y), f2bf(b.z), f2bf(b.w)};
    *(uint4*)(out + (size_t)i * 8) = *(const uint4*)u;
}

// ---------------------------------------------------------------------------
// C(fp32, M x N) = A_bf16(M,K) @ B_bf16(N,K)^T (+bias)
// 128x128 tile, BK=32, 4 waves, each wave 64x64 (4x4 MFMA 16x16x32).
// ---------------------------------------------------------------------------
static __device__ __forceinline__ void gemm_body(
        u16* As, u16* Bs,
        const u16* __restrict__ A, const u16* __restrict__ B,
        const float* __restrict__ bias, float* __restrict__ C,
        int N, int K, int m0, int n0) {
    const int t    = threadIdx.x;
    const int lane = t & 63, w = t >> 6;
    const int l15  = lane & 15, quad = lane >> 4;
    const int wr   = w >> 1, wc = w & 1;

    f32x4 acc[4][4];
#pragma unroll
    for (int mt = 0; mt < 4; ++mt)
#pragma unroll
        for (int nt = 0; nt < 4; ++nt) acc[mt][nt] = (f32x4){0.f, 0.f, 0.f, 0.f};

    const int off0 = w*2048 + lane*16;
    const int r0 = off0 >> 6,          c0 = (off0 & 63) >> 1;
    const int r1 = (off0+1024) >> 6,   c1 = ((off0+1024) & 63) >> 1;
    const u16* Ag0 = A + (size_t)(m0 + r0) * K + c0;
    const u16* Ag1 = A + (size_t)(m0 + r1) * K + c1;
    const u16* Bg0 = B + (size_t)(n0 + r0) * K + c0;
    const u16* Bg1 = B + (size_t)(n0 + r1) * K + c1;
    char* AsB = (char*)As; char* BsB = (char*)Bs;
    const int ldsOff0 = w*2048, ldsOff1 = w*2048 + 1024;

    for (int k0 = 0; k0 < K; k0 += 32) {
        gll16(Ag0 + k0, AsB + ldsOff0);
        gll16(Ag1 + k0, AsB + ldsOff1);
        gll16(Bg0 + k0, BsB + ldsOff0);
        gll16(Bg1 + k0, BsB + ldsOff1);
        __syncthreads();
        bf16x8 af[4], bf[4];
#pragma unroll
        for (int mt = 0; mt < 4; ++mt)
            af[mt] = __builtin_bit_cast(bf16x8,
                *(const uint4*)&As[(wr*64 + mt*16 + l15)*32 + quad*8]);
#pragma unroll
        for (int nt = 0; nt < 4; ++nt)
            bf[nt] = __builtin_bit_cast(bf16x8,
                *(const uint4*)&Bs[(wc*64 + nt*16 + l15)*32 + quad*8]);
#pragma unroll
        for (int mt = 0; mt < 4; ++mt)
#pragma unroll
            for (int nt = 0; nt < 4; ++nt)
                acc[mt][nt] = __builtin_amdgcn_mfma_f32_16x16x32_bf16(
                                  af[mt], bf[nt], acc[mt][nt], 0, 0, 0);
        __syncthreads();
    }

#pragma unroll
    for (int mt = 0; mt < 4; ++mt)
#pragma unroll
        for (int nt = 0; nt < 4; ++nt) {
            const int col = n0 + wc*64 + nt*16 + l15;
            const float bv = bias ? bias[col] : 0.f;
#pragma unroll
            for (int r = 0; r < 4; ++r) {
                const int row = m0 + wr*64 + mt*16 + quad*4 + r;
                C[(size_t)row * N + col] = acc[mt][nt][r] + bv;
            }
        }
}

__global__ __launch_bounds__(256)
void gemm_nt_bf16(const u16* __restrict__ A, const u16* __restrict__ B,
                  const float* __restrict__ bias, float* __restrict__ C,
                  int N, int K) {
    __shared__ __align__(16) u16 As[128*32];
    __shared__ __align__(16) u16 Bs[128*32];
    gemm_body(As, Bs, A, B, bias, C, N, K, blockIdx.y*128, blockIdx.x*128);
}

__global__ __launch_bounds__(256)
void gemm_nt_bf16_kv(const u16* __restrict__ A,
                     const u16* __restrict__ Bk, const u16* __restrict__ Bv,
                     float* __restrict__ Ck, float* __restrict__ Cv,
                     int N, int K) {
    __shared__ __align__(16) u16 As[128*32];
    __shared__ __align__(16) u16 Bs[128*32];
    const u16* B = blockIdx.z ? Bv : Bk;
    float*     C = blockIdx.z ? Cv : Ck;
    gemm_body(As, Bs, A, B, nullptr, C, N, K, blockIdx.y*128, blockIdx.x*128);
}

// ---------------------------------------------------------------------------
// RMSNorm + RoPE, fp32 in -> bf16 out (pre-scaled by `scale`).
// ---------------------------------------------------------------------------
__global__ __launch_bounds__(256)
void rmsnorm_rope_cast(const float* __restrict__ in, const float* __restrict__ w,
                       u16* __restrict__ out, int nheads, float scale) {
    const int row  = blockIdx.x * 4 + (threadIdx.x >> 6);
    const int lane = threadIdx.x & 63;
    const float* p = in + (size_t)row * 128;
    float x1 = p[lane], x2 = p[lane + 64];
    float ss = x1*x1 + x2*x2;
#pragma unroll
    for (int off = 32; off >= 1; off >>= 1) ss += __shfl_xor(ss, off, 64);
    float inv = 1.0f / (sqrtf(ss * (1.0f/128.0f)) + 1e-6f);
    float x1n = w[lane]      * x1 * inv;
    float x2n = w[lane + 64] * x2 * inv;
    int tpos = (row / nheads) & (T_SEQ - 1);
    float invfreq = powf(10000.0f, -(float)lane / 64.0f);
    float s, c;
    sincosf((float)tpos * invfreq, &s, &c);
    out[(size_t)row*128 + lane]      = f2bf((x1n * c + x2n * s) * scale);
    out[(size_t)row*128 + lane + 64] = f2bf((x2n * c - x1n * s) * scale);
}

// ---------------------------------------------------------------------------
// V cast fp32->bf16 + transpose: v (B,T,G,D) -> vt (B,G,D,T).
// ---------------------------------------------------------------------------
__global__ __launch_bounds__(256)
void v_cast_transpose(const float* __restrict__ v, u16* __restrict__ vt) {
    __shared__ u16 Lt[128 * 66];
    const int t  = threadIdx.x;
    const int t0 = blockIdx.x * 64;
    const int bg = blockIdx.y;
    const int b  = bg / NG, g = bg % NG;
#pragma unroll
    for (int rep = 0; rep < 8; ++rep) {
        int idx = rep * 256 + t;
        int i   = idx >> 5;
        int c   = idx & 31;
        float4 f = *(const float4*)(v + ((size_t)(b*T_SEQ + t0 + i)*NG + g)*DH + c*4);
        Lt[(c*4+0)*66 + i] = f2bf(f.x);
        Lt[(c*4+1)*66 + i] = f2bf(f.y);
        Lt[(c*4+2)*66 + i] = f2bf(f.z);
        Lt[(c*4+3)*66 + i] = f2bf(f.w);
    }
    __syncthreads();
#pragma unroll
    for (int rep = 0; rep < 4; ++rep) {
        int idx = rep * 256 + t;
        int d = idx >> 3, c = idx & 7;
        const u16* src = &Lt[d*66 + c*8];
        uint4 val;
        val.x = *(const unsigned int*)(src + 0);
        val.y = *(const unsigned int*)(src + 2);
        val.z = *(const unsigned int*)(src + 4);
        val.w = *(const unsigned int*)(src + 6);
        *(uint4*)(vt + ((size_t)(bg*DH + d))*T_SEQ + t0 + c*8) = val;
    }
}

// ---------------------------------------------------------------------------
// MFMA flash attention v4: GQA-shared staging + CU load balance + reg prefetch.
// Block = 512 thr = 8 waves = 4 heads (one group) x 32 queries.
// chunk mapping pairs heavy(b=0) with light(b=1) on the same CU:
//   b=0 rows take chunk 63-x, b=1 rows take chunk x  -> per-CU work ~constant.
// K/V tile t+1 is prefetched into VGPRs while tile t computes.
// ---------------------------------------------------------------------------
#define KPAD 136
#define VPAD 72
#define PPAD 72

__global__ __launch_bounds__(512)
void flash_attn_mfma(const u16* __restrict__ qh, const u16* __restrict__ kh,
                     const u16* __restrict__ vt, u16* __restrict__ y) {
    __shared__ __align__(16) u16 Ks [64  * KPAD];   // 64 keys x 128 d
    __shared__ __align__(16) u16 Vts[128 * VPAD];   // 128 d  x 64 keys
    __shared__ __align__(16) u16 Ps [128 * PPAD];   // 8 waves x 16 rows x 64 keys

    const int t    = threadIdx.x;
    const int lane = t & 63, w = t >> 6;            // w = 0..7
    const int l15  = lane & 15, quad = lane >> 4;
    const int bg   = blockIdx.y;
    const int b    = bg >> 2, g = bg & 3;
    const int chunk = b ? (int)blockIdx.x : (63 - (int)blockIdx.x);
    const int q0   = chunk * 32;
    const int h    = g * (NH / NG) + (w & 3);
    const int qrow0 = q0 + (w >> 2) * 16;

    const float L2E = 1.4426950408889634f;

    bf16x8 aq[4];
    const u16* qp = qh + ((size_t)(b*T_SEQ + qrow0 + l15) * NH + h) * DH;
#pragma unroll
    for (int kc = 0; kc < 4; ++kc)
        aq[kc] = __builtin_bit_cast(bf16x8, *(const uint4*)(qp + kc*32 + quad*8));

    f32x4 accO[8];
#pragma unroll
    for (int nd = 0; nd < 8; ++nd) accO[nd] = (f32x4){0.f, 0.f, 0.f, 0.f};
    float ls[4] = {0.f, 0.f, 0.f, 0.f};

    // staging geometry (fixed per thread)
    const int kr = t >> 4, kc16 = t & 15;           // K: rows kr, kr+32
    const int vd = t >> 3, vc8  = t & 7;            // V: d-rows vd, vd+64
    const u16* kgb = kh + ((size_t)b*T_SEQ*NG + g)*DH;
    const u16* vgb = vt + ((size_t)(b*NG + g)*DH)*T_SEQ;

    uint4 kreg0, kreg1, vreg0, vreg1;
    {   // prefetch tile 0
        kreg0 = *(const uint4*)(kgb + (size_t)(0 + kr)      * NG*DH + kc16*8);
        kreg1 = *(const uint4*)(kgb + (size_t)(0 + kr + 32) * NG*DH + kc16*8);
        vreg0 = *(const uint4*)(vgb + (size_t)vd       * T_SEQ + 0 + vc8*8);
        vreg1 = *(const uint4*)(vgb + (size_t)(vd + 64)* T_SEQ + 0 + vc8*8);
    }

    const int ktiles = q0 / 64 + 1;
    for (int kt = 0; kt < ktiles; ++kt) {
        // --- regs -> LDS ---
        *(uint4*)&Ks [ kr      *KPAD + kc16*8] = kreg0;
        *(uint4*)&Ks [(kr + 32)*KPAD + kc16*8] = kreg1;
        *(uint4*)&Vts[ vd      *VPAD + vc8*8]  = vreg0;
        *(uint4*)&Vts[(vd + 64)*VPAD + vc8*8]  = vreg1;
        __syncthreads();

        // --- prefetch tile kt+1 (overlaps compute below) ---
        if (kt + 1 < ktiles) {
            const int k1 = (kt + 1) * 64;
            kreg0 = *(const uint4*)(kgb + (size_t)(k1 + kr)      * NG*DH + kc16*8);
            kreg1 = *(const uint4*)(kgb + (size_t)(k1 + kr + 32) * NG*DH + kc16*8);
            vreg0 = *(const uint4*)(vgb + (size_t)vd       * T_SEQ + k1 + vc8*8);
            vreg1 = *(const uint4*)(vgb + (size_t)(vd + 64)* T_SEQ + k1 + vc8*8);
        }

        const int k0 = kt * 64;
        // --- S = Q K^T (16x64 per wave) ---
        f32x4 accS[4];
#pragma unroll
        for (int nt = 0; nt < 4; ++nt) accS[nt] = (f32x4){0.f, 0.f, 0.f, 0.f};
#pragma unroll
        for (int nt = 0; nt < 4; ++nt)
#pragma unroll
            for (int kc = 0; kc < 4; ++kc) {
                bf16x8 bk = __builtin_bit_cast(bf16x8,
                    *(const uint4*)&Ks[(nt*16 + l15)*KPAD + kc*32 + quad*8]);
                accS[nt] = __builtin_amdgcn_mfma_f32_16x16x32_bf16(aq[kc], bk, accS[nt], 0, 0, 0);
            }

        // --- soft-cap (poly tanh) + causal + exp2, accumulate row sums ---
#pragma unroll
        for (int nt = 0; nt < 4; ++nt) {
            const int colg = k0 + nt*16 + l15;
#pragma unroll
            for (int r = 0; r < 4; ++r) {
                const int rowg = qrow0 + quad*4 + r;
                float s = accS[nt][r];
                float z = s * 0.02f;          // s/50
                float u = z * z;              // <= ~0.052
                float poly = fmaf(u, fmaf(u, fmaf(u, -0.05396825396825397f,
                                       0.13333333333333333f),
                                      -0.3333333333333333f), 1.0f);
                float p = __builtin_amdgcn_exp2f(s * poly * L2E);
                p = (colg > rowg) ? 0.f : p;
                ls[r] += p;
                Ps[(w*16 + quad*4 + r)*PPAD + nt*16 + l15] = f2bf(p);
            }
        }

        bf16x8 ap[2];
#pragma unroll
        for (int kc = 0; kc < 2; ++kc)
            ap[kc] = __builtin_bit_cast(bf16x8,
                *(const uint4*)&Ps[(w*16 + l15)*PPAD + kc*32 + quad*8]);

#pragma unroll
        for (int nd = 0; nd < 8; ++nd)
#pragma unroll
            for (int kc = 0; kc < 2; ++kc) {
                bf16x8 bv = __builtin_bit_cast(bf16x8,
                    *(const uint4*)&Vts[(nd*16 + l15)*VPAD + kc*32 + quad*8]);
                accO[nd] = __builtin_amdgcn_mfma_f32_16x16x32_bf16(ap[kc], bv, accO[nd], 0, 0, 0);
            }
        __syncthreads();
    }

    // --- final row-sum reduction across the 16 l15 lanes ---
#pragma unroll
    for (int r = 0; r < 4; ++r) {
        float v = ls[r];
        v += __shfl_xor(v, 1, 64);
        v += __shfl_xor(v, 2, 64);
        v += __shfl_xor(v, 4, 64);
        v += __shfl_xor(v, 8, 64);
        ls[r] = v;
    }

#pragma unroll
    for (int r = 0; r < 4; ++r) {
        float invl = 1.f / ls[r];
        u16* yp = y + (size_t)(b*T_SEQ + qrow0 + quad*4 + r) * C_DIM + h*DH;
#pragma unroll
        for (int nd = 0; nd < 8; ++nd)
            yp[nd*16 + l15] = f2bf(accO[nd][r] * invl);
    }
}

// ---------------------------------------------------------------------------
extern "C" void kernel_launch(void* const* d_in, const int* in_sizes, int n_in,
                              void* d_out, int out_size, void* d_ws, size_t ws_size,
                              hipStream_t stream) {
    const float* x  = (const float*)d_in[0];
    const float* Wq = (const float*)d_in[1];
    const float* Wk = (const float*)d_in[2];
    const float* Wv = (const float*)d_in[3];
    const float* Wo = (const float*)d_in[4];
    const float* bo = (const float*)d_in[5];
    const float* qw = (const float*)d_in[6];
    const float* kw = (const float*)d_in[7];
    float* out = (float*)d_out;

    const size_t qE = (size_t)BATCH * T_SEQ * NH * DH;   // 8,388,608
    const size_t kE = (size_t)BATCH * T_SEQ * NG * DH;   // 2,097,152
    const size_t wqE = (size_t)C_DIM * C_DIM;            // 4,194,304
    const size_t wkE = (size_t)(NG*DH) * C_DIM;          // 1,048,576

    float* qf  = (float*)d_ws;          // qE floats
    float* kf  = qf + qE;               // kE floats
    float* vf  = kf + kE;               // kE floats
    u16*   qh  = (u16*)(vf + kE);       // qE
    u16*   khb = qh + qE;               // kE
    u16*   vtb = khb + kE;              // kE
    u16*   xh  = vtb + kE;              // qE
    u16*   wqh = xh + qE;               // wqE
    u16*   wkh = wqh + wqE;             // wkE
    u16*   wvh = wkh + wkE;             // wkE
    u16*   woh = (u16*)kf;              // wqE (reuses kf: dead after rmsnorm_k)
    u16*   yh  = (u16*)qf;              // qE  (reuses qf: dead after rmsnorm_q)

    const int M = BATCH * T_SEQ;   // 4096
    dim3 blk(256);

    cast_f32_bf16<<<dim3(qE/8/256),  blk, 0, stream>>>(x,  xh,  qE/8);
    cast_f32_bf16<<<dim3(wqE/8/256), blk, 0, stream>>>(Wq, wqh, wqE/8);
    cast_f32_bf16<<<dim3(wkE/8/256), blk, 0, stream>>>(Wk, wkh, wkE/8);
    cast_f32_bf16<<<dim3(wkE/8/256), blk, 0, stream>>>(Wv, wvh, wkE/8);

    gemm_nt_bf16<<<dim3(C_DIM/128, M/128), blk, 0, stream>>>(xh, wqh, nullptr, qf, C_DIM, C_DIM);
    gemm_nt_bf16_kv<<<dim3((NG*DH)/128, M/128, 2), blk, 0, stream>>>(xh, wkh, wvh, kf, vf, NG*DH, C_DIM);

    rmsnorm_rope_cast<<<dim3(M * NH / 4), blk, 0, stream>>>(qf, qw, qh, NH, 0.08838834764831845f);
    rmsnorm_rope_cast<<<dim3(M * NG / 4), blk, 0, stream>>>(kf, kw, khb, NG, 1.0f);
    v_cast_transpose<<<dim3(T_SEQ/64, BATCH*NG), blk, 0, stream>>>(vf, vtb);

    cast_f32_bf16<<<dim3(wqE/8/256), blk, 0, stream>>>(Wo, woh, wqE/8);

    flash_attn_mfma<<<dim3(T_SEQ/32, BATCH*NG), dim3(512), 0, stream>>>(qh, khb, vtb, yh);

    gemm_nt_bf16<<<dim3(C_DIM/128, M/128), blk, 0, stream>>>(yh, woh, bo, out, C_DIM, C_DIM);
}